// Round 3
// baseline (59.478 us; speedup 1.0000x reference)
//
#include <hip/hip_runtime.h>
#include <math.h>

#define NBATCH 2048
#define GS 14
#define NCELL (GS * GS)      // 196
#define NCH 30
#define NPRED (NCELL * NCH)  // 5880 floats per batch
#define MAXOBJ 20
#define NCLS 20

// Access pred register pair array with compile-time index
#define P(i) (((i) & 1) ? pr[(i) >> 1].y : pr[(i) >> 1].x)

// ---------------------------------------------------------------------------
// Fused kernel: one block per batch element.
//  Phase A (lanes 0..19): decode objects from target -> LDS object list.
//  Phase B (tid<196): each cell thread holds its 30 pred floats in registers,
//   scans the object list in order (LDS broadcast reads) -> reproduces the
//   reference's sequential last-write-wins per cell, computes loss partials.
//  Tail: shuffle+LDS reduce -> partials row; last block (counter mod 2048)
//   reduces all 2048 rows and writes the scalar loss.
// partials[b*8+k]: 0=s_noobj 1=c_noobj 2=s_objconf 3=s_xy 4=s_wh 5=s_clc 6=c_obj
// ---------------------------------------------------------------------------
__global__ __launch_bounds__(256) void yolo_fused_kernel(
        const float* __restrict__ pred,
        const float* __restrict__ target,
        float* __restrict__ partials,
        unsigned int* __restrict__ counter,
        float* __restrict__ out)
{
    __shared__ int   s_obj_cell[MAXOBJ];
    __shared__ float s_obj_dat[MAXOBJ][4];   // offx,offy,w,h
    __shared__ int   s_obj_cls[MAXOBJ];
    __shared__ float s_red[4][8];
    __shared__ float s_fin[256][8];          // finisher tree (8 KB)
    __shared__ unsigned int s_last;

    const int b = blockIdx.x;
    const int tid = threadIdx.x;
    const float fg = (float)GS;

    // ---- issue per-cell pred loads early (in flight during phase A) ----
    float2 pr[15];
    if (tid < NCELL) {
        const float2* pc2 = (const float2*)(pred + (size_t)b * NPRED + tid * NCH);
        #pragma unroll
        for (int i = 0; i < 15; ++i) pr[i] = pc2[i];
    }

    // ---- phase A: object decode (target only) ----
    if (tid < MAXOBJ) {
        const float* tb = target + (size_t)b * (MAXOBJ * 5) + tid * 5;
        float x1 = tb[0], y1 = tb[1], x2 = tb[2], y2 = tb[3], cf = tb[4];
        int cell = -1;
        float offx = 0.f, offy = 0.f, w = 0.f, h = 0.f;
        if ((x1 + y1 + x2 + y2 + cf) != 0.0f) {
            float cx = (x1 + x2) * 0.5f * fg;
            float cy = (y1 + y2) * 0.5f * fg;
            w = x2 - x1;
            h = y2 - y1;
            int gx = min(max((int)floorf(cx), 0), GS - 1);
            int gy = min(max((int)floorf(cy), 0), GS - 1);
            offx = cx - (float)gx;
            offy = cy - (float)gy;
            cell = gy * GS + gx;
        }
        s_obj_cell[tid] = cell;
        s_obj_dat[tid][0] = offx;
        s_obj_dat[tid][1] = offy;
        s_obj_dat[tid][2] = w;
        s_obj_dat[tid][3] = h;
        s_obj_cls[tid] = (int)cf;
    }
    __syncthreads();

    // ---- phase B: per-cell target resolution + loss partials ----
    float v[7] = {0.f, 0.f, 0.f, 0.f, 0.f, 0.f, 0.f};
    if (tid < NCELL) {
        int flag0 = 0, flag1 = 0;
        float b0x = 0.f, b0y = 0.f, b0w = 0.f, b0h = 0.f;
        float b1x = 0.f, b1y = 0.f, b1w = 0.f, b1h = 0.f;
        unsigned int clsmask = 0u;
        for (int o = 0; o < MAXOBJ; ++o) {
            if (s_obj_cell[o] == tid) {   // broadcast read; matches <=1 lane
                float offx = s_obj_dat[o][0], offy = s_obj_dat[o][1];
                float w = s_obj_dat[o][2],  h = s_obj_dat[o][3];
                float tcx = offx / fg, tcy = offy / fg;
                float tlx = tcx - 0.5f * w, tly = tcy - 0.5f * h;
                float trx = tcx + 0.5f * w, trY = tcy + 0.5f * h;
                float ta = (trx - tlx) * (trY - tly);
                float iou0, iou1;
                {
                    float px = P(1) / fg, py = P(2) / fg;
                    float pw = P(3), ph = P(4);
                    float plx = px - 0.5f * pw, ply = py - 0.5f * ph;
                    float prx = px + 0.5f * pw, prY = py + 0.5f * ph;
                    float ix = fmaxf(fminf(prx, trx) - fmaxf(plx, tlx), 0.f);
                    float iy = fmaxf(fminf(prY, trY) - fmaxf(ply, tly), 0.f);
                    float inter = ix * iy;
                    float a1 = (prx - plx) * (prY - ply);
                    iou0 = inter / (a1 + ta - inter);
                }
                {
                    float px = P(6) / fg, py = P(7) / fg;
                    float pw = P(8), ph = P(9);
                    float plx = px - 0.5f * pw, ply = py - 0.5f * ph;
                    float prx = px + 0.5f * pw, prY = py + 0.5f * ph;
                    float ix = fmaxf(fminf(prx, trx) - fmaxf(plx, tlx), 0.f);
                    float iy = fmaxf(fminf(prY, trY) - fmaxf(ply, tly), 0.f);
                    float inter = ix * iy;
                    float a1 = (prx - plx) * (prY - ply);
                    iou1 = inter / (a1 + ta - inter);
                }
                if (iou1 > iou0) { flag1 = 1; b1x = offx; b1y = offy; b1w = w; b1h = h; }
                else             { flag0 = 1; b0x = offx; b0y = offy; b0w = w; b0h = h; }
                clsmask |= 1u << s_obj_cls[o];
            }
        }
        int nset = flag0 + flag1;
        if (nset == 0) {
            v[0] = P(0) * P(0) + P(5) * P(5);
            v[1] = 1.0f;
        } else if (nset == 1) {
            float conf = flag1 ? P(5) : P(0);
            float px   = flag1 ? P(6) : P(1);
            float py   = flag1 ? P(7) : P(2);
            float pw   = flag1 ? P(8) : P(3);
            float ph   = flag1 ? P(9) : P(4);
            float bx = flag1 ? b1x : b0x;
            float by = flag1 ? b1y : b0y;
            float bw = flag1 ? b1w : b0w;
            float bh = flag1 ? b1h : b0h;
            float dconf = conf - 1.0f;
            v[2] = dconf * dconf;
            float dx = px - bx, dy = py - by;
            v[3] = dx * dx + dy * dy;
            float sw = sqrtf(pw) - sqrtf(bw);
            float sh = sqrtf(ph) - sqrtf(bh);
            v[4] = sw * sw + sh * sh;
            float clc = 0.f;
            #pragma unroll
            for (int c = 0; c < NCLS; ++c) {
                float t = ((clsmask >> c) & 1u) ? 1.0f : 0.0f;
                float d = P(10 + c) - t;
                clc += d * d;
            }
            v[5] = clc;
            v[6] = 1.0f;
        }
        // nset == 2: excluded from every loss term
    }

    // ---- wave shuffle reduce, cross-wave via LDS ----
    #pragma unroll
    for (int off = 32; off > 0; off >>= 1) {
        #pragma unroll
        for (int k = 0; k < 7; ++k) v[k] += __shfl_down(v[k], off);
    }
    const int wave = tid >> 6;
    if ((tid & 63) == 0) {
        #pragma unroll
        for (int k = 0; k < 7; ++k) s_red[wave][k] = v[k];
    }
    __syncthreads();
    if (tid == 0) {
        float* p = partials + (size_t)b * 8;
        #pragma unroll
        for (int k = 0; k < 7; ++k)
            p[k] = s_red[0][k] + s_red[1][k] + s_red[2][k] + s_red[3][k];
        p[7] = 0.0f;
        __threadfence();                       // release partials
        unsigned int old = atomicAdd(counter, 1u);
        s_last = ((old & (NBATCH - 1)) == (NBATCH - 1)) ? 1u : 0u;
    }
    __syncthreads();

    // ---- last arriving block does the final reduction ----
    if (s_last) {
        __threadfence();                       // acquire partials
        float4 a0 = {0.f, 0.f, 0.f, 0.f};
        float4 a1 = {0.f, 0.f, 0.f, 0.f};
        for (int r = tid; r < NBATCH; r += 256) {
            const float4* p = (const float4*)(partials + (size_t)r * 8);
            float4 x0 = p[0];
            float4 x1 = p[1];
            a0.x += x0.x; a0.y += x0.y; a0.z += x0.z; a0.w += x0.w;
            a1.x += x1.x; a1.y += x1.y; a1.z += x1.z; a1.w += x1.w;
        }
        s_fin[tid][0] = a0.x; s_fin[tid][1] = a0.y; s_fin[tid][2] = a0.z; s_fin[tid][3] = a0.w;
        s_fin[tid][4] = a1.x; s_fin[tid][5] = a1.y; s_fin[tid][6] = a1.z; s_fin[tid][7] = a1.w;
        __syncthreads();
        for (int s = 128; s > 0; s >>= 1) {
            if (tid < s) {
                #pragma unroll
                for (int k = 0; k < 7; ++k) s_fin[tid][k] += s_fin[tid + s][k];
            }
            __syncthreads();
        }
        if (tid == 0) {
            float s_noobj   = s_fin[0][0];
            float c_noobj   = s_fin[0][1];
            float s_objconf = s_fin[0][2];
            float s_xy      = s_fin[0][3];
            float s_wh      = s_fin[0][4];
            float s_clc     = s_fin[0][5];
            float c_obj     = s_fin[0][6];
            float n_noobj = 2.0f * c_noobj;
            float n_resp  = c_obj;
            float noobj_loss   = s_noobj / n_noobj;
            float objconf_loss = s_objconf / n_resp;
            float loss_xy  = s_xy / (n_resp * 2.0f);
            float loss_wh  = s_wh / (n_resp * 2.0f);
            float loss_clc = s_clc / (c_obj * (float)NCLS);
            out[0] = 5.0f * (loss_xy + loss_wh) + objconf_loss
                   + 0.5f * noobj_loss + loss_clc;
        }
    }
}

// ---------------------------------------------------------------------------
// Fallback final-reduce kernel (used only if ws_size is too small for the
// counter word — keeps correctness independent of harness scratch sizing).
// ---------------------------------------------------------------------------
__global__ __launch_bounds__(256) void yolo_final_kernel(
        const float* __restrict__ partials,
        float* __restrict__ out)
{
    __shared__ float red[256][8];
    const int tid = threadIdx.x;
    float4 a0 = {0.f, 0.f, 0.f, 0.f};
    float4 a1 = {0.f, 0.f, 0.f, 0.f};
    for (int r = tid; r < NBATCH; r += 256) {
        const float4* p = (const float4*)(partials + (size_t)r * 8);
        float4 x0 = p[0];
        float4 x1 = p[1];
        a0.x += x0.x; a0.y += x0.y; a0.z += x0.z; a0.w += x0.w;
        a1.x += x1.x; a1.y += x1.y; a1.z += x1.z; a1.w += x1.w;
    }
    red[tid][0] = a0.x; red[tid][1] = a0.y; red[tid][2] = a0.z; red[tid][3] = a0.w;
    red[tid][4] = a1.x; red[tid][5] = a1.y; red[tid][6] = a1.z; red[tid][7] = a1.w;
    __syncthreads();
    for (int s = 128; s > 0; s >>= 1) {
        if (tid < s) {
            #pragma unroll
            for (int k = 0; k < 7; ++k) red[tid][k] += red[tid + s][k];
        }
        __syncthreads();
    }
    if (tid == 0) {
        float s_noobj   = red[0][0];
        float c_noobj   = red[0][1];
        float s_objconf = red[0][2];
        float s_xy      = red[0][3];
        float s_wh      = red[0][4];
        float s_clc     = red[0][5];
        float c_obj     = red[0][6];
        float n_noobj = 2.0f * c_noobj;
        float n_resp  = c_obj;
        float noobj_loss   = s_noobj / n_noobj;
        float objconf_loss = s_objconf / n_resp;
        float loss_xy  = s_xy / (n_resp * 2.0f);
        float loss_wh  = s_wh / (n_resp * 2.0f);
        float loss_clc = s_clc / (c_obj * (float)NCLS);
        out[0] = 5.0f * (loss_xy + loss_wh) + objconf_loss
               + 0.5f * noobj_loss + loss_clc;
    }
}

extern "C" void kernel_launch(void* const* d_in, const int* in_sizes, int n_in,
                              void* d_out, int out_size, void* d_ws, size_t ws_size,
                              hipStream_t stream) {
    const float* pred = (const float*)d_in[0];
    const float* target = (const float*)d_in[1];
    float* partials = (float*)d_ws;                      // 2048*8 f32 = 64 KiB
    unsigned int* counter = (unsigned int*)((char*)d_ws + NBATCH * 8 * sizeof(float));
    float* out = (float*)d_out;

    if (ws_size >= NBATCH * 8 * sizeof(float) + sizeof(unsigned int)) {
        // Fused path: counter mod-2048 selects the last block per call, for
        // ANY initial counter value (incl. 0xAA poison) since each call adds
        // exactly 2048 and 2048 | 2^32. Output is order-independent -> deterministic.
        yolo_fused_kernel<<<NBATCH, 256, 0, stream>>>(pred, target, partials, counter, out);
    } else {
        yolo_fused_kernel<<<NBATCH, 256, 0, stream>>>(pred, target, partials, counter, out);
        yolo_final_kernel<<<1, 256, 0, stream>>>(partials, out);
    }
}